// Round 1
// baseline (1125.852 us; speedup 1.0000x reference)
//
#include <hip/hip_runtime.h>
#include <stdint.h>

#define NA 50000
#define NE 320000
#define AD 32
#define BD 64

// workspace layout (uint32 slots)
#define WS_FLAG   0
#define WS_COUNTS 16
#define WS_CURSOR (WS_COUNTS + NA)           // 50016
#define WS_OFFS   (WS_CURSOR + NA)           // 100016, NA+1 entries
#define WS_EIDS   150048                     // aligned, NE entries
// total ≈ 470048 u32 ≈ 1.83 MB

__device__ __forceinline__ void load_pair(const void* p, int e, int mode, int& s, int& d){
  if (mode){ const int* q = (const int*)p; s = q[2*e]; d = q[2*e+1]; }
  else     { const long long* q = (const long long*)p; s = (int)q[2*e]; d = (int)q[2*e+1]; }
}

// detect int32 vs int64 pair_indices: int64 -> odd 32-bit words are all 0
__global__ void k_detect(const void* pairs, uint32_t* ws){
  const uint32_t* w = (const uint32_t*)pairs;
  uint32_t x = 0;
  for (int i = threadIdx.x; i < 2048; i += 256) x |= w[2*i + 1];
  __shared__ uint32_t sh[256];
  sh[threadIdx.x] = x; __syncthreads();
  for (int s = 128; s > 0; s >>= 1){
    if (threadIdx.x < s) sh[threadIdx.x] |= sh[threadIdx.x + s];
    __syncthreads();
  }
  if (threadIdx.x == 0) ws[WS_FLAG] = (sh[0] != 0u) ? 1u : 0u;  // 1 = int32 mode
}

__global__ void k_hist(const void* pairs, uint32_t* ws){
  int e = blockIdx.x * 256 + threadIdx.x;
  if (e >= NE) return;
  int mode = (int)ws[WS_FLAG];
  int s, d; load_pair(pairs, e, mode, s, d);
  atomicAdd(&ws[WS_COUNTS + s], 1u);
}

// single-block exclusive scan of counts[NA] -> offs[NA+1]
__global__ void k_scan(uint32_t* ws){
  const uint32_t* counts = ws + WS_COUNTS;
  uint32_t* offs = ws + WS_OFFS;
  __shared__ uint32_t wsum[16];
  __shared__ uint32_t carrysh;
  const int tid = threadIdx.x; const int lane = tid & 63; const int wid = tid >> 6;
  if (tid == 0) carrysh = 0u;
  __syncthreads();
  for (int base = 0; base < NA; base += 8192){
    uint32_t v[8]; uint32_t tot = 0u;
    int i0 = base + tid * 8;
    #pragma unroll
    for (int j = 0; j < 8; ++j){ int i = i0 + j; v[j] = (i < NA) ? counts[i] : 0u; tot += v[j]; }
    uint32_t inc = tot;
    #pragma unroll
    for (int m = 1; m < 64; m <<= 1){ uint32_t t = __shfl_up(inc, m); if (lane >= m) inc += t; }
    if (lane == 63) wsum[wid] = inc;
    __syncthreads();
    if (wid == 0){
      uint32_t w = (lane < 16) ? wsum[lane] : 0u;
      #pragma unroll
      for (int m = 1; m < 16; m <<= 1){ uint32_t t = __shfl_up(w, m); if (lane >= m) w += t; }
      if (lane < 16) wsum[lane] = w;     // inclusive over waves
    }
    __syncthreads();
    uint32_t waveoff = (wid == 0) ? 0u : wsum[wid - 1];
    uint32_t run = carrysh + waveoff + (inc - tot);
    #pragma unroll
    for (int j = 0; j < 8; ++j){ int i = i0 + j; if (i < NA) offs[i] = run; run += v[j]; }
    __syncthreads();
    if (tid == 0) carrysh += wsum[15];
    __syncthreads();
  }
  if (tid == 0) offs[NA] = carrysh;
}

__global__ void k_scatter(const void* pairs, uint32_t* ws){
  int e = blockIdx.x * 256 + threadIdx.x;
  if (e >= NE) return;
  int mode = (int)ws[WS_FLAG];
  int s, d; load_pair(pairs, e, mode, s, d);
  uint32_t p = atomicAdd(&ws[WS_CURSOR + s], 1u);
  ws[WS_EIDS + ws[WS_OFFS + s] + p] = (uint32_t)e;
}

// main: 512 threads = 8 waves, each wave owns 2 atoms.
// lane = (kk = lane&7, jq = lane>>3); R[c][jj] holds R[k=8c+kk][j=jq*4+jj]
__launch_bounds__(512)
__global__ void k_main(const float* __restrict__ atoms, const float* __restrict__ bonds,
                       const void* __restrict__ pairs, const float* __restrict__ Kg,
                       const float* __restrict__ bias, float* __restrict__ out,
                       const uint32_t* __restrict__ ws){
  __shared__ float Ksh[8 * 1024];        // one 8-row K chunk (32 KB)
  __shared__ float red[8 * 520];         // per-wave transpose scratch, padded rows of 65

  const int tid  = threadIdx.x;
  const int lane = tid & 63;
  const int wid  = tid >> 6;             // 0..7
  const int kk   = lane & 7;
  const int jq   = lane >> 3;            // 0..7
  const int mode = (int)ws[WS_FLAG];
  const uint32_t* offs = ws + WS_OFFS;
  const uint32_t* eids = ws + WS_EIDS;

  const int a0 = blockIdx.x * 16 + wid * 2;   // grid = NA/16 = 3125 exactly
  const int a1 = a0 + 1;

  float R0[8][4], R1[8][4], S0[4], S1[4];
  #pragma unroll
  for (int c = 0; c < 8; ++c)
    #pragma unroll
    for (int j = 0; j < 4; ++j){ R0[c][j] = 0.f; R1[c][j] = 0.f; }
  #pragma unroll
  for (int j = 0; j < 4; ++j){ S0[j] = 0.f; S1[j] = 0.f; }

  // ---- R/S accumulation over this atom's edges ----
  #pragma unroll
  for (int sel = 0; sel < 2; ++sel){
    const int a = sel ? a1 : a0;
    const uint32_t beg = offs[a], end = offs[a + 1];
    for (uint32_t t = beg; t < end; ++t){
      const int e = (int)eids[t];
      int s_, d_; load_pair(pairs, e, mode, s_, d_);
      const float4 av = *(const float4*)&atoms[d_ * AD + jq * 4];
      float b[8];
      #pragma unroll
      for (int c = 0; c < 8; ++c) b[c] = bonds[e * BD + c * 8 + kk];
      if (sel == 0){
        #pragma unroll
        for (int c = 0; c < 8; ++c){
          R0[c][0] += b[c] * av.x; R0[c][1] += b[c] * av.y;
          R0[c][2] += b[c] * av.z; R0[c][3] += b[c] * av.w;
        }
        if (kk == 0){ S0[0] += av.x; S0[1] += av.y; S0[2] += av.z; S0[3] += av.w; }
      } else {
        #pragma unroll
        for (int c = 0; c < 8; ++c){
          R1[c][0] += b[c] * av.x; R1[c][1] += b[c] * av.y;
          R1[c][2] += b[c] * av.z; R1[c][3] += b[c] * av.w;
        }
        if (kk == 0){ S1[0] += av.x; S1[1] += av.y; S1[2] += av.z; S1[3] += av.w; }
      }
    }
  }

  // ---- contraction with K, 8 chunks of 8 rows staged in LDS ----
  float acc0[32], acc1[32];
  #pragma unroll
  for (int i = 0; i < 32; ++i){ acc0[i] = 0.f; acc1[i] = 0.f; }

  #pragma unroll
  for (int c = 0; c < 8; ++c){
    __syncthreads();
    #pragma unroll
    for (int q = 0; q < 4; ++q){
      int f4 = tid + q * 512;            // 0..2047 float4s
      int word = f4 * 4;
      int row = word >> 10;
      int col = word & 1023;
      *(float4*)&Ksh[word] = *(const float4*)&Kg[(8 * c + row) * 1024 + col];
    }
    __syncthreads();
    #pragma unroll
    for (int i = 0; i < 32; ++i){
      const float4 kv = *(const float4*)&Ksh[kk * 1024 + i * 32 + jq * 4];
      acc0[i] += kv.x * R0[c][0] + kv.y * R0[c][1] + kv.z * R0[c][2] + kv.w * R0[c][3];
      acc1[i] += kv.x * R1[c][0] + kv.y * R1[c][1] + kv.z * R1[c][2] + kv.w * R1[c][3];
    }
  }

  // ---- bias term: out[i] += Σ_j bias[i*32+j] * S[j] (only kk==0 lanes hold S) ----
  if (kk == 0){
    #pragma unroll
    for (int i = 0; i < 32; ++i){
      const float4 bv = *(const float4*)&bias[i * 32 + jq * 4];
      acc0[i] += bv.x * S0[0] + bv.y * S0[1] + bv.z * S0[2] + bv.w * S0[3];
      acc1[i] += bv.x * S1[0] + bv.y * S1[1] + bv.z * S1[2] + bv.w * S1[3];
    }
  }

  // ---- cross-lane reduction via per-wave LDS transpose, write output ----
  float* myred = &red[wid * 520];
  auto epi = [&](const float (&acc)[32], int a){
    #pragma unroll
    for (int g = 0; g < 4; ++g){
      #pragma unroll
      for (int ii = 0; ii < 8; ++ii) myred[ii * 65 + lane] = acc[g * 8 + ii];
      // single-wave LDS ordering is guaranteed by hardware lgkmcnt waits
      const int ii = lane & 7, seg = lane >> 3;
      float p = 0.f;
      #pragma unroll
      for (int t2 = 0; t2 < 8; ++t2) p += myred[ii * 65 + seg * 8 + t2];
      p += __shfl_xor(p, 8);
      p += __shfl_xor(p, 16);
      p += __shfl_xor(p, 32);
      if (lane < 8) out[a * 32 + g * 8 + lane] = p;
    }
  };
  epi(acc0, a0);
  epi(acc1, a1);
}

extern "C" void kernel_launch(void* const* d_in, const int* in_sizes, int n_in,
                              void* d_out, int out_size, void* d_ws, size_t ws_size,
                              hipStream_t stream){
  const float* atoms = (const float*)d_in[0];
  const float* bonds = (const float*)d_in[1];
  const void*  pairs = d_in[2];
  const float* Kg    = (const float*)d_in[3];
  const float* bias  = (const float*)d_in[4];
  float* out = (float*)d_out;
  uint32_t* ws = (uint32_t*)d_ws;

  hipMemsetAsync(ws + WS_COUNTS, 0, sizeof(uint32_t) * 2 * NA, stream);  // counts + cursor
  k_detect<<<1, 256, 0, stream>>>(pairs, ws);
  k_hist<<<(NE + 255) / 256, 256, 0, stream>>>(pairs, ws);
  k_scan<<<1, 1024, 0, stream>>>(ws);
  k_scatter<<<(NE + 255) / 256, 256, 0, stream>>>(pairs, ws);
  k_main<<<NA / 16, 512, 0, stream>>>(atoms, bonds, pairs, Kg, bias, out, ws);
}